// Round 1
// baseline (386.961 us; speedup 1.0000x reference)
//
#include <hip/hip_runtime.h>
#include <math.h>

// Problem constants (from reference)
#define F_END   20          // POOL/N_TASKS * 1
#define TOPK    10
#define E_P_LEN 8
#define KEY_D   768
#define P_FEAT  9216        // EMB_D * HEADS
#define P_ROW   (E_P_LEN * P_FEAT)   // 73728 floats per pool row
#define HALF_ROW (P_ROW / 2)         // 36864 (Ek / Ev split)
#define BQ      1024        // B*Q = 4*256
#define EPS     1e-12f

// ---------------------------------------------------------------------------
// Kernel 1: per-query scores -> top-10 -> softmax -> dense gate [BQ][20]
// One block (256 thr = 4 waves) per query. Wave w computes scores for
// k = w*5 .. w*5+4; wave 0 then does top-k + softmax + gate write.
// ---------------------------------------------------------------------------
__global__ __launch_bounds__(256) void score_gate_kernel(
    const float* __restrict__ x,    // [BQ][KEY_D]
    const float* __restrict__ K,    // [POOL][KEY_D] (use first 20 rows)
    const float* __restrict__ A,    // [POOL][KEY_D]
    float* __restrict__ gate)       // [BQ][F_END] out
{
    const int q    = blockIdx.x;
    const int wave = threadIdx.x >> 6;
    const int lane = threadIdx.x & 63;
    __shared__ float s_score[F_END];

    // Each lane owns d = lane*4 + i*256, i<3 (float4, coalesced).
    const float4* x4 = (const float4*)(x + (size_t)q * KEY_D);
    float4 xf[3];
#pragma unroll
    for (int i = 0; i < 3; ++i) xf[i] = x4[lane + i * 64];

#pragma unroll
    for (int kk = 0; kk < 5; ++kk) {
        const int k = wave * 5 + kk;
        const float4* A4 = (const float4*)(A + (size_t)k * KEY_D);
        const float4* K4 = (const float4*)(K + (size_t)k * KEY_D);
        float num = 0.f, den = 0.f, kden = 0.f;
#pragma unroll
        for (int i = 0; i < 3; ++i) {
            float4 a  = A4[lane + i * 64];
            float4 kv = K4[lane + i * 64];
            float xa;
            xa = xf[i].x * a.x; num += xa * kv.x; den += xa * xa; kden += kv.x * kv.x;
            xa = xf[i].y * a.y; num += xa * kv.y; den += xa * xa; kden += kv.y * kv.y;
            xa = xf[i].z * a.z; num += xa * kv.z; den += xa * xa; kden += kv.z * kv.z;
            xa = xf[i].w * a.w; num += xa * kv.w; den += xa * xa; kden += kv.w * kv.w;
        }
        // full-wave butterfly reduction of the three partials
#pragma unroll
        for (int off = 32; off; off >>= 1) {
            num  += __shfl_xor(num,  off);
            den  += __shfl_xor(den,  off);
            kden += __shfl_xor(kden, off);
        }
        if (lane == 0) {
            float dn = fmaxf(sqrtf(den), EPS) * fmaxf(sqrtf(kden), EPS);
            s_score[k] = num / dn;
        }
    }
    __syncthreads();

    if (wave == 0) {
        // lanes 0..19 hold one score each
        float myv = (lane < F_END) ? s_score[lane] : -INFINITY;
        bool  sel = false;
        float my_e = 0.f, vmax = 0.f, esum = 0.f;
#pragma unroll
        for (int j = 0; j < TOPK; ++j) {
            float bv = myv; int bi = lane;
#pragma unroll
            for (int off = 32; off; off >>= 1) {
                float ov = __shfl_xor(bv, off);
                int   oi = __shfl_xor(bi, off);
                if (ov > bv || (ov == bv && oi < bi)) { bv = ov; bi = oi; }
            }
            if (j == 0) vmax = bv;            // first extracted = max
            float e = expf(bv - vmax);
            esum += e;
            if (lane == bi) { sel = true; my_e = e; myv = -INFINITY; }
        }
        if (lane < F_END)
            gate[(size_t)q * F_END + lane] = sel ? (my_e / esum) : 0.f;
    }
}

// ---------------------------------------------------------------------------
// Kernel 2: out[bq, f] = sum_k gate[bq,k] * p[k, f]   (tiny-K GEMM, K=20)
// Thread owns one float4 column f4; keeps all 20 p-values in registers
// (80 VGPR) and loops over M_TILE queries, reading the uniform gate row
// via the scalar path. Output layout: Ek block then Ev block.
// grid = (72 f-chunks, 16 m-tiles), block = 256.
// ---------------------------------------------------------------------------
#define M_TILE 64

__global__ __launch_bounds__(256) void expand_kernel(
    const float* __restrict__ p,     // [POOL][P_ROW]
    const float* __restrict__ gate,  // [BQ][F_END]
    float* __restrict__ out)         // Ek [BQ][HALF_ROW] ++ Ev [BQ][HALF_ROW]
{
    const int f4 = blockIdx.x * 256 + threadIdx.x;   // [0, 18432)
    const int f  = f4 * 4;                           // float index in p row
    const int h  = (f >= HALF_ROW) ? 1 : 0;          // 0 = Ek, 1 = Ev
    const int fl = f - h * HALF_ROW;                 // local offset in half

    // preload the 20 p columns for this f4
    float4 pc[F_END];
#pragma unroll
    for (int k = 0; k < F_END; ++k)
        pc[k] = *(const float4*)(p + (size_t)k * P_ROW + f);

    const int m0 = blockIdx.y * M_TILE;
    float* outbase = out + (size_t)h * BQ * HALF_ROW + fl;

    for (int m = 0; m < M_TILE; ++m) {
        const float* __restrict__ g = gate + (size_t)(m0 + m) * F_END;
        float4 acc = {0.f, 0.f, 0.f, 0.f};
#pragma unroll
        for (int k = 0; k < F_END; ++k) {
            const float gv = g[k];
            acc.x += gv * pc[k].x;
            acc.y += gv * pc[k].y;
            acc.z += gv * pc[k].z;
            acc.w += gv * pc[k].w;
        }
        *(float4*)(outbase + (size_t)(m0 + m) * HALF_ROW) = acc;
    }
}

// ---------------------------------------------------------------------------
extern "C" void kernel_launch(void* const* d_in, const int* in_sizes, int n_in,
                              void* d_out, int out_size, void* d_ws, size_t ws_size,
                              hipStream_t stream) {
    const float* x_querry = (const float*)d_in[0];   // [4,256,768]
    // d_in[1] = l (unused), d_in[2] = x_block (unused)
    const float* Kp = (const float*)d_in[3];         // [100,768]
    const float* Ap = (const float*)d_in[4];         // [100,768]
    const float* pp = (const float*)d_in[5];         // [100,8,9216]
    float* out = (float*)d_out;                      // 75,497,472 floats

    float* gate = (float*)d_ws;                      // BQ*F_END floats = 80 KB

    score_gate_kernel<<<BQ, 256, 0, stream>>>(x_querry, Kp, Ap, gate);

    dim3 grid2(P_ROW / (256 * 4), BQ / M_TILE);      // (72, 16)
    expand_kernel<<<grid2, 256, 0, stream>>>(pp, gate, out);
}

// Round 4
// 338.344 us; speedup vs baseline: 1.1437x; 1.1437x over previous
//
#include <hip/hip_runtime.h>
#include <math.h>

// Problem constants (from reference)
#define F_END   20          // POOL/N_TASKS * 1
#define TOPK    10
#define E_P_LEN 8
#define KEY_D   768
#define P_FEAT  9216        // EMB_D * HEADS
#define P_ROW   (E_P_LEN * P_FEAT)   // 73728 floats per pool row
#define HALF_ROW (P_ROW / 2)         // 36864 (Ek / Ev split)
#define BQ      1024        // B*Q = 4*256
#define EPS     1e-12f

typedef float floatx4 __attribute__((ext_vector_type(4)));   // native vector: OK for nontemporal builtins

// ---------------------------------------------------------------------------
// Kernel 1: per-query scores -> top-10 -> softmax -> dense gate [BQ][20]
// One block (256 thr = 4 waves) per query. Wave w computes scores for
// k = w*5 .. w*5+4; wave 0 then does top-k + softmax + gate write.
// ---------------------------------------------------------------------------
__global__ __launch_bounds__(256) void score_gate_kernel(
    const float* __restrict__ x,    // [BQ][KEY_D]
    const float* __restrict__ K,    // [POOL][KEY_D] (use first 20 rows)
    const float* __restrict__ A,    // [POOL][KEY_D]
    float* __restrict__ gate)       // [BQ][F_END] out
{
    const int q    = blockIdx.x;
    const int wave = threadIdx.x >> 6;
    const int lane = threadIdx.x & 63;
    __shared__ float s_score[F_END];

    // Each lane owns d = lane*4 + i*256, i<3 (float4, coalesced).
    const float4* x4 = (const float4*)(x + (size_t)q * KEY_D);
    float4 xf[3];
#pragma unroll
    for (int i = 0; i < 3; ++i) xf[i] = x4[lane + i * 64];

#pragma unroll
    for (int kk = 0; kk < 5; ++kk) {
        const int k = wave * 5 + kk;
        const float4* A4 = (const float4*)(A + (size_t)k * KEY_D);
        const float4* K4 = (const float4*)(K + (size_t)k * KEY_D);
        float num = 0.f, den = 0.f, kden = 0.f;
#pragma unroll
        for (int i = 0; i < 3; ++i) {
            float4 a  = A4[lane + i * 64];
            float4 kv = K4[lane + i * 64];
            float xa;
            xa = xf[i].x * a.x; num += xa * kv.x; den += xa * xa; kden += kv.x * kv.x;
            xa = xf[i].y * a.y; num += xa * kv.y; den += xa * xa; kden += kv.y * kv.y;
            xa = xf[i].z * a.z; num += xa * kv.z; den += xa * xa; kden += kv.z * kv.z;
            xa = xf[i].w * a.w; num += xa * kv.w; den += xa * xa; kden += kv.w * kv.w;
        }
        // full-wave butterfly reduction of the three partials
#pragma unroll
        for (int off = 32; off; off >>= 1) {
            num  += __shfl_xor(num,  off);
            den  += __shfl_xor(den,  off);
            kden += __shfl_xor(kden, off);
        }
        if (lane == 0) {
            float dn = fmaxf(sqrtf(den), EPS) * fmaxf(sqrtf(kden), EPS);
            s_score[k] = num / dn;
        }
    }
    __syncthreads();

    if (wave == 0) {
        // lanes 0..19 hold one score each
        float myv = (lane < F_END) ? s_score[lane] : -INFINITY;
        bool  sel = false;
        float my_e = 0.f, vmax = 0.f, esum = 0.f;
#pragma unroll
        for (int j = 0; j < TOPK; ++j) {
            float bv = myv; int bi = lane;
#pragma unroll
            for (int off = 32; off; off >>= 1) {
                float ov = __shfl_xor(bv, off);
                int   oi = __shfl_xor(bi, off);
                if (ov > bv || (ov == bv && oi < bi)) { bv = ov; bi = oi; }
            }
            if (j == 0) vmax = bv;            // first extracted = max
            float e = expf(bv - vmax);
            esum += e;
            if (lane == bi) { sel = true; my_e = e; myv = -INFINITY; }
        }
        if (lane < F_END)
            gate[(size_t)q * F_END + lane] = sel ? (my_e / esum) : 0.f;
    }
}

// ---------------------------------------------------------------------------
// Kernel 2: out[bq, f] = sum_k gate[bq,k] * p[k, f]   (tiny-K GEMM, K=20)
// Thread owns one float4 column; 20 p-values live in registers (80 VGPR).
// m-loop unrolled x4: 4 independent acc/store streams for store pipelining.
// Nontemporal stores keep p resident in L2.
// grid = (72 f-chunks, 16 m-tiles), block = 256.
// ---------------------------------------------------------------------------
#define M_TILE 64

__global__ __launch_bounds__(256) void expand_kernel(
    const float* __restrict__ p,     // [POOL][P_ROW]
    const float* __restrict__ gate,  // [BQ][F_END]
    float* __restrict__ out)         // Ek [BQ][HALF_ROW] ++ Ev [BQ][HALF_ROW]
{
    const int f4 = blockIdx.x * 256 + threadIdx.x;   // [0, 18432)
    const int f  = f4 * 4;                           // float index in p row
    const int h  = (f >= HALF_ROW) ? 1 : 0;          // 0 = Ek, 1 = Ev (uniform per block)
    const int fl = f - h * HALF_ROW;                 // local offset in half

    // preload the 20 p columns for this f4
    floatx4 pc[F_END];
#pragma unroll
    for (int k = 0; k < F_END; ++k)
        pc[k] = *(const floatx4*)(p + (size_t)k * P_ROW + f);

    const int m0 = blockIdx.y * M_TILE;
    const float* __restrict__ gbase = gate + (size_t)m0 * F_END;
    float* ob = out + (size_t)h * BQ * HALF_ROW + (size_t)m0 * HALF_ROW + fl;

#pragma unroll 1
    for (int mm = 0; mm < M_TILE; mm += 4) {
        floatx4 acc0 = {0,0,0,0}, acc1 = {0,0,0,0}, acc2 = {0,0,0,0}, acc3 = {0,0,0,0};
        const float* __restrict__ g0 = gbase + (size_t)(mm + 0) * F_END;
        const float* __restrict__ g1 = gbase + (size_t)(mm + 1) * F_END;
        const float* __restrict__ g2 = gbase + (size_t)(mm + 2) * F_END;
        const float* __restrict__ g3 = gbase + (size_t)(mm + 3) * F_END;
#pragma unroll
        for (int k = 0; k < F_END; ++k) {
            const floatx4 pk = pc[k];
            acc0 += g0[k] * pk;
            acc1 += g1[k] * pk;
            acc2 += g2[k] * pk;
            acc3 += g3[k] * pk;
        }
        __builtin_nontemporal_store(acc0, (floatx4*)(ob + (size_t)(mm + 0) * HALF_ROW));
        __builtin_nontemporal_store(acc1, (floatx4*)(ob + (size_t)(mm + 1) * HALF_ROW));
        __builtin_nontemporal_store(acc2, (floatx4*)(ob + (size_t)(mm + 2) * HALF_ROW));
        __builtin_nontemporal_store(acc3, (floatx4*)(ob + (size_t)(mm + 3) * HALF_ROW));
    }
}

// ---------------------------------------------------------------------------
extern "C" void kernel_launch(void* const* d_in, const int* in_sizes, int n_in,
                              void* d_out, int out_size, void* d_ws, size_t ws_size,
                              hipStream_t stream) {
    const float* x_querry = (const float*)d_in[0];   // [4,256,768]
    // d_in[1] = l (unused), d_in[2] = x_block (unused)
    const float* Kp = (const float*)d_in[3];         // [100,768]
    const float* Ap = (const float*)d_in[4];         // [100,768]
    const float* pp = (const float*)d_in[5];         // [100,8,9216]
    float* out = (float*)d_out;                      // 75,497,472 floats

    float* gate = (float*)d_ws;                      // BQ*F_END floats = 80 KB

    score_gate_kernel<<<BQ, 256, 0, stream>>>(x_querry, Kp, Ap, gate);

    dim3 grid2(P_ROW / (256 * 4), BQ / M_TILE);      // (72, 16)
    expand_kernel<<<grid2, 256, 0, stream>>>(pp, gate, out);
}